// Round 2
// baseline (6311.844 us; speedup 1.0000x reference)
//
#include <hip/hip_runtime.h>

#define SEQ   1024
#define DIN   64
#define NHID  256
#define NBLK  64
#define NTHR  512

typedef _Float16 f16x8 __attribute__((ext_vector_type(8)));
typedef float    f32x4 __attribute__((ext_vector_type(4)));

#define MFMA16(a,b,c) __builtin_amdgcn_mfma_f32_16x16x32_f16((a),(b),(c),0,0,0)

__device__ __forceinline__ float sigm(float v){
  return __builtin_amdgcn_rcpf(1.f + __expf(-v));
}
__device__ __forceinline__ float tanh_f(float v){
  return 1.f - 2.f*__builtin_amdgcn_rcpf(__expf(2.f*v)+1.f);
}

__device__ __forceinline__ f16x8 cvt8(f32x4 a, f32x4 b){
  f16x8 r;
  r[0]=(_Float16)a[0]; r[1]=(_Float16)a[1]; r[2]=(_Float16)a[2]; r[3]=(_Float16)a[3];
  r[4]=(_Float16)b[0]; r[5]=(_Float16)b[1]; r[6]=(_Float16)b[2]; r[7]=(_Float16)b[3];
  return r;
}

union U32H2 { unsigned int u; _Float16 h[2]; unsigned short us[2]; };

// 64 blocks = 16 groups (16 batch rows) x 4 members (64 hidden cols = 256 gate rows).
// Transposed MFMA: D[m=gate-rows(interleaved jl*4+gate), n=batch16] = W' . h^T.
// Lane (l15,lhi) of m-tile mt holds gates f,i,g,o (r=0..3) for batch=l15, jl=mt*4+lhi
// -> pointwise fully in-register; c never leaves VGPRs.
__global__ void __launch_bounds__(NTHR, 2)
lstm_seq(const float* __restrict__ x, const float* __restrict__ h0,
         const float* __restrict__ c0, const float* __restrict__ Wi,
         const float* __restrict__ bi, const float* __restrict__ Wh,
         const float* __restrict__ bh, const float* __restrict__ Wcls,
         const float* __restrict__ bcls,
         int* __restrict__ flags, unsigned short* __restrict__ slices,
         float* __restrict__ out)
{
  // h double-buffer: [parity][batch(16) x 128 u32 (256 f16 cols)], XOR-swizzled
  __shared__ __align__(16) unsigned int hbuf[2][16*128];

  const int bid = blockIdx.x;
  const int grp = bid & 15;          // batch group (16 rows)
  const int q   = bid >> 4;          // hidden quarter 0..3
  const int tid = threadIdx.x;
  const int w   = tid >> 6;          // wave 0..7
  const int l   = tid & 63;
  const int l15 = l & 15;
  const int lhi = l >> 4;

  // ---- A-frags: weights, register-resident f16, gate-interleaved rows ----
  // rho = mt*16 + l15 ; orig weight row = (rho&3)*256 + q*64 + (rho>>2)
  f16x8 wa[2][8], xa[2][2];
#pragma unroll
  for (int t=0;t<2;t++){
    const int rho = (w*2+t)*16 + l15;
    const int row = (rho&3)*NHID + q*64 + (rho>>2);
#pragma unroll
    for (int kt=0;kt<8;kt++){
      const float* p = Wh + row*NHID + kt*32 + lhi*8;
      wa[t][kt] = cvt8(*(const f32x4*)p, *(const f32x4*)(p+4));
    }
#pragma unroll
    for (int kt=0;kt<2;kt++){
      const float* p = Wi + row*DIN + kt*32 + lhi*8;
      xa[t][kt] = cvt8(*(const f32x4*)p, *(const f32x4*)(p+4));
    }
  }

  // per-lane biases and cell state (this lane owns (batch=l15, jl = mt*4+lhi))
  float bsum[2][4], c[2];
#pragma unroll
  for (int t=0;t<2;t++){
    const int jl = (w*2+t)*4 + lhi;
#pragma unroll
    for (int g=0; g<4; g++)
      bsum[t][g] = bi[g*NHID + q*64 + jl] + bh[g*NHID + q*64 + jl];
    c[t] = c0[(size_t)(grp*16+l15)*NHID + q*64 + jl];
  }

  // h0 -> hbuf[0] (packed f16 pairs, swizzled: word ^= (batch&7)<<2)
  for (int i=tid; i<16*128; i+=NTHR){
    const int b = i>>7, cp = i&127;
    U32H2 pk;
    pk.h[0] = (_Float16)h0[(size_t)(grp*16+b)*NHID + cp*2];
    pk.h[1] = (_Float16)h0[(size_t)(grp*16+b)*NHID + cp*2 + 1];
    hbuf[0][i ^ ((b&7)<<2)] = pk.u;
  }
  __syncthreads();

  // x prefetch: B-frag needs x[batch=l15, k=kt*32+lhi*8+j]
  const float* xrow = x + (size_t)(grp*16 + l15) * (SEQ*DIN);
  f32x4 xp0,xp1,xp2,xp3;
  {
    const float* p = xrow + lhi*8;
    xp0 = *(const f32x4*)p;      xp1 = *(const f32x4*)(p+4);
    xp2 = *(const f32x4*)(p+32); xp3 = *(const f32x4*)(p+36);
  }

  const int fs = (grp*4 + q)*16;

  for (int s=0; s<SEQ; s++){
    const unsigned int* hr = hbuf[s&1];
    unsigned int*       hw = hbuf[(s+1)&1];

    // issue B-frag reads from swizzled LDS (balanced banks)
    f16x8 hb[8];
#pragma unroll
    for (int kt=0;kt<8;kt++){
      const int word = (l15*128 + kt*16 + lhi*4) ^ ((l15&7)<<2);
      hb[kt] = *(const f16x8*)(hr + word);
    }
    // x MFMAs first (no LDS dependence) while ds_reads are in flight
    f32x4 acc0 = {0.f,0.f,0.f,0.f}, acc1 = {0.f,0.f,0.f,0.f};
    {
      f16x8 xb0 = cvt8(xp0, xp1), xb1 = cvt8(xp2, xp3);
      acc0 = MFMA16(xa[0][0], xb0, acc0);
      acc0 = MFMA16(xa[0][1], xb1, acc0);
      acc1 = MFMA16(xa[1][0], xb0, acc1);
      acc1 = MFMA16(xa[1][1], xb1, acc1);
    }
    // prefetch x for s+1 (latency hidden under h-MFMAs)
    {
      const int sn = (s < SEQ-1) ? s+1 : s;
      const float* p = xrow + sn*DIN + lhi*8;
      xp0 = *(const f32x4*)p;      xp1 = *(const f32x4*)(p+4);
      xp2 = *(const f32x4*)(p+32); xp3 = *(const f32x4*)(p+36);
    }
#pragma unroll
    for (int kt=0;kt<8;kt++){
      acc0 = MFMA16(wa[0][kt], hb[kt], acc0);
      acc1 = MFMA16(wa[1][kt], hb[kt], acc1);
    }

    // ---- pointwise, fully in-register (gate r: 0=f,1=i,2=g,3=o) ----
    unsigned short h16[2];
    {
      const float f0 = sigm (acc0[0] + bsum[0][0]);
      const float i0 = sigm (acc0[1] + bsum[0][1]);
      const float g0 = tanh_f(acc0[2] + bsum[0][2]);
      const float o0 = sigm (acc0[3] + bsum[0][3]);
      c[0] = c[0]*f0 + i0*g0;
      U32H2 u; u.h[0] = (_Float16)(tanh_f(c[0])*o0); h16[0] = u.us[0];
      const float f1 = sigm (acc1[0] + bsum[1][0]);
      const float i1 = sigm (acc1[1] + bsum[1][1]);
      const float g1 = tanh_f(acc1[2] + bsum[1][2]);
      const float o1 = sigm (acc1[3] + bsum[1][3]);
      c[1] = c[1]*f1 + i1*g1;
      U32H2 u2; u2.h[0] = (_Float16)(tanh_f(c[1])*o1); h16[1] = u2.us[0];
    }
    // own h -> hw (swizzled b16 writes) + publish to partners
#pragma unroll
    for (int t=0;t<2;t++){
      const int jl  = (w*2+t)*4 + lhi;
      const int byte = (l15*512 + (q*64 + jl)*2) ^ ((l15&7)<<4);
      *(unsigned short*)((char*)hw + byte) = h16[t];
      __hip_atomic_store(&slices[((size_t)(s&1)*NBLK + grp*4 + q)*1024 + l15*64 + jl],
                         h16[t], __ATOMIC_RELAXED, __HIP_MEMORY_SCOPE_AGENT);
    }
    __syncthreads();   // drain publishes (vmcnt) + own hw writes visible
    if (tid == 0)
      __hip_atomic_store(&flags[fs], s+1, __ATOMIC_RELEASE, __HIP_MEMORY_SCOPE_AGENT);

    // exchange: wave v (0..2) polls partner (q+1+v)&3, then loads its slice
    if (w < 3){
      const int qq = (q + 1 + w) & 3;
      while (__hip_atomic_load(&flags[(grp*4+qq)*16], __ATOMIC_ACQUIRE,
                               __HIP_MEMORY_SCOPE_AGENT) <= s) {}
      const unsigned int* sp = (const unsigned int*)slices
                             + ((size_t)(s&1)*NBLK + grp*4 + qq)*512;
#pragma unroll
      for (int i=0;i<8;i++){
        const unsigned int v = __hip_atomic_load(sp + i*64 + l, __ATOMIC_RELAXED,
                                                 __HIP_MEMORY_SCOPE_AGENT);
        const int w32 = i*64 + l;
        const int b = w32 >> 5, cp = w32 & 31;   // batch, colpair within quarter
        hw[(b*128 + qq*32 + cp) ^ ((b&7)<<2)] = v;
      }
    }
    __syncthreads();   // h(s) complete in hw
  }

  // classifier: q==0 blocks hold the full final h in hbuf[SEQ&1]
  if (q == 0 && tid < 160){
    const int b = tid/10, j = tid - b*10;
    const unsigned int* hf = hbuf[SEQ&1];
    float sum = bcls[j];
    for (int cp=0; cp<128; cp++){
      U32H2 v; v.u = hf[(b*128 + cp) ^ ((b&7)<<2)];
      sum += Wcls[j*NHID + cp*2]     * (float)v.h[0]
           + Wcls[j*NHID + cp*2 + 1] * (float)v.h[1];
    }
    out[(grp*16+b)*10 + j] = sum;
  }
}

extern "C" void kernel_launch(void* const* d_in, const int* in_sizes, int n_in,
                              void* d_out, int out_size, void* d_ws, size_t ws_size,
                              hipStream_t stream){
  const float* x    = (const float*)d_in[0];
  const float* h0   = (const float*)d_in[1];
  const float* c0   = (const float*)d_in[2];
  const float* Wi   = (const float*)d_in[3];
  const float* bi   = (const float*)d_in[4];
  const float* Wh   = (const float*)d_in[5];
  const float* bh   = (const float*)d_in[6];
  const float* Wcls = (const float*)d_in[7];
  const float* bcls = (const float*)d_in[8];

  char* ws = (char*)d_ws;
  int*            flags  = (int*)ws;                      // 64 flags, 64B apart: 4096 B
  unsigned short* slices = (unsigned short*)(ws + 4096);  // 2 x 64 x 1024 u16 = 262144 B

  hipMemsetAsync(flags, 0, 4096, stream);  // flags must start at 0 every call
  hipLaunchKernelGGL(lstm_seq, dim3(NBLK), dim3(NTHR), 0, stream,
                     x, h0, c0, Wi, bi, Wh, bh, Wcls, bcls,
                     flags, slices, (float*)d_out);
}

// Round 3
// 3592.438 us; speedup vs baseline: 1.7570x; 1.7570x over previous
//
#include <hip/hip_runtime.h>

#define SEQ   1024
#define DIN   64
#define NHID  256
#define NBLK  64
#define NTHR  512

typedef _Float16 f16x8 __attribute__((ext_vector_type(8)));
typedef float    f32x4 __attribute__((ext_vector_type(4)));

#define MFMA16(a,b,c) __builtin_amdgcn_mfma_f32_16x16x32_f16((a),(b),(c),0,0,0)

__device__ __forceinline__ float sigm(float v){
  return __builtin_amdgcn_rcpf(1.f + __expf(-v));
}
__device__ __forceinline__ float tanh_f(float v){
  return 1.f - 2.f*__builtin_amdgcn_rcpf(__expf(2.f*v)+1.f);
}

__device__ __forceinline__ f16x8 cvt8(f32x4 a, f32x4 b){
  f16x8 r;
  r[0]=(_Float16)a[0]; r[1]=(_Float16)a[1]; r[2]=(_Float16)a[2]; r[3]=(_Float16)a[3];
  r[4]=(_Float16)b[0]; r[5]=(_Float16)b[1]; r[6]=(_Float16)b[2]; r[7]=(_Float16)b[3];
  return r;
}

union U32H2 { unsigned int u; _Float16 h[2]; unsigned short us[2]; };

// 64 blocks = 16 groups (16 batch rows) x 4 members (64 hidden cols = 256 gate rows).
// Transposed MFMA D = W'.h^T with row permutation m -> (gate = m&3,
// jl = (m>>5)*8 + ((m>>2)&3)*2 + ((m>>4)&1)) so lane (l15,lhi) of wave w owns
// gates f,i,g,o of the ADJACENT col-pair jl = w*8+lhi*2+{0,1} for batch l15:
// pointwise in-register, h publish = one coalesced u32 per lane.
__global__ void __launch_bounds__(NTHR, 2)
lstm_seq(const float* __restrict__ x, const float* __restrict__ h0,
         const float* __restrict__ c0, const float* __restrict__ Wi,
         const float* __restrict__ bi, const float* __restrict__ Wh,
         const float* __restrict__ bh, const float* __restrict__ Wcls,
         const float* __restrict__ bcls,
         int* __restrict__ flags, unsigned int* __restrict__ slices,
         float* __restrict__ out)
{
  // h double-buffer: [parity][batch(16) x 128 u32 (256 f16 cols)], word ^= (b&7)<<2
  __shared__ __align__(16) unsigned int hbuf[2][16*128];

  const int bid = blockIdx.x;
  const int grp = bid & 15;          // batch group (16 rows)
  const int q   = bid >> 4;          // hidden quarter 0..3
  const int tid = threadIdx.x;
  const int w   = tid >> 6;          // wave 0..7
  const int l   = tid & 63;
  const int l15 = l & 15;
  const int lhi = l >> 4;

  // ---- A-frags: weights, register-resident f16, permuted rows ----
  f16x8 wa[2][8], xa[2][2];
#pragma unroll
  for (int t=0;t<2;t++){
    const int mt  = w*2 + t;
    const int mr  = l15;                              // A-frag row within tile
    const int jl  = (mt>>1)*8 + ((mr>>2)<<1) + (mt&1);
    const int row = (mr&3)*NHID + q*64 + jl;          // original weight row
#pragma unroll
    for (int kt=0;kt<8;kt++){
      const float* p = Wh + row*NHID + kt*32 + lhi*8;
      wa[t][kt] = cvt8(*(const f32x4*)p, *(const f32x4*)(p+4));
    }
#pragma unroll
    for (int kt=0;kt<2;kt++){
      const float* p = Wi + row*DIN + kt*32 + lhi*8;
      xa[t][kt] = cvt8(*(const f32x4*)p, *(const f32x4*)(p+4));
    }
  }

  // per-lane bias (as acc init) and cell state; lane owns jl = w*8+lhi*2+t
  f32x4 binit0, binit1; float c[2];
#pragma unroll
  for (int t=0;t<2;t++){
    const int jl = w*8 + lhi*2 + t;
    f32x4 bv;
#pragma unroll
    for (int g=0; g<4; g++)
      bv[g] = bi[g*NHID + q*64 + jl] + bh[g*NHID + q*64 + jl];
    if (t==0) binit0 = bv; else binit1 = bv;
    c[t] = c0[(size_t)(grp*16+l15)*NHID + q*64 + jl];
  }

  // h0 -> hbuf[0]
  for (int i=tid; i<16*128; i+=NTHR){
    const int b = i>>7, cp = i&127;
    U32H2 pk;
    pk.h[0] = (_Float16)h0[(size_t)(grp*16+b)*NHID + cp*2];
    pk.h[1] = (_Float16)h0[(size_t)(grp*16+b)*NHID + cp*2 + 1];
    hbuf[0][i ^ ((b&7)<<2)] = pk.u;
  }
  __syncthreads();

  // x prefetch: B-frag x[batch=l15, k=kt*32+lhi*8+j]
  const float* xrow = x + (size_t)(grp*16 + l15) * (SEQ*DIN);
  f32x4 xp0,xp1,xp2,xp3;
  {
    const float* p = xrow + lhi*8;
    xp0 = *(const f32x4*)p;      xp1 = *(const f32x4*)(p+4);
    xp2 = *(const f32x4*)(p+32); xp3 = *(const f32x4*)(p+36);
  }

  const int fs = (grp*4 + q)*16;

  for (int s=0; s<SEQ; s++){
    const unsigned int* hr = hbuf[s&1];
    unsigned int*       hw = hbuf[(s+1)&1];

    // B-frag reads (swizzled, balanced banks)
    f16x8 hb[8];
#pragma unroll
    for (int kt=0;kt<8;kt++){
      const int word = (l15*128 + kt*16 + lhi*4) ^ ((l15&7)<<2);
      hb[kt] = *(const f16x8*)(hr + word);
    }
    f32x4 acc0 = binit0, acc1 = binit1;   // bias pre-folded
    {
      f16x8 xb0 = cvt8(xp0, xp1), xb1 = cvt8(xp2, xp3);
      acc0 = MFMA16(xa[0][0], xb0, acc0);
      acc0 = MFMA16(xa[0][1], xb1, acc0);
      acc1 = MFMA16(xa[1][0], xb0, acc1);
      acc1 = MFMA16(xa[1][1], xb1, acc1);
    }
    // prefetch x for s+1
    {
      const int sn = (s < SEQ-1) ? s+1 : s;
      const float* p = xrow + sn*DIN + lhi*8;
      xp0 = *(const f32x4*)p;      xp1 = *(const f32x4*)(p+4);
      xp2 = *(const f32x4*)(p+32); xp3 = *(const f32x4*)(p+36);
    }
#pragma unroll
    for (int kt=0;kt<8;kt++){
      acc0 = MFMA16(wa[0][kt], hb[kt], acc0);
      acc1 = MFMA16(wa[1][kt], hb[kt], acc1);
    }

    // ---- pointwise in-register (r: 0=f,1=i,2=g,3=o) ----
    U32H2 pk;
    {
      const float f0 = sigm (acc0[0]);
      const float i0 = sigm (acc0[1]);
      const float g0 = tanh_f(acc0[2]);
      const float o0 = sigm (acc0[3]);
      c[0] = c[0]*f0 + i0*g0;
      pk.h[0] = (_Float16)(tanh_f(c[0])*o0);
      const float f1 = sigm (acc1[0]);
      const float i1 = sigm (acc1[1]);
      const float g1 = tanh_f(acc1[2]);
      const float o1 = sigm (acc1[3]);
      c[1] = c[1]*f1 + i1*g1;
      pk.h[1] = (_Float16)(tanh_f(c[1])*o1);
    }
    // own col-pair -> hw + coalesced u32 publish (slice word = w*64 + l)
    {
      const int jp = w*4 + lhi;
      hw[(l15*128 + q*32 + jp) ^ ((l15&7)<<2)] = pk.u;
      __hip_atomic_store(slices + ((size_t)(s&1)*NBLK + grp*4 + q)*512 + jp*16 + l15,
                         pk.u, __ATOMIC_RELAXED, __HIP_MEMORY_SCOPE_AGENT);
    }
    __syncthreads();   // drain publishes (vmcnt) + own hw LDS writes
    if (tid == 0)
      __hip_atomic_store(&flags[fs], s+1, __ATOMIC_RELEASE, __HIP_MEMORY_SCOPE_AGENT);

    // exchange: wave w (0..2) polls partner (q+1+w)&3, loads its 2KB slice
    if (w < 3){
      const int qq = (q + 1 + w) & 3;
      while (__hip_atomic_load(&flags[(grp*4+qq)*16], __ATOMIC_ACQUIRE,
                               __HIP_MEMORY_SCOPE_AGENT) <= s) {}
      const uint4* sp = (const uint4*)(slices + ((size_t)(s&1)*NBLK + grp*4 + qq)*512);
#pragma unroll
      for (int it=0; it<2; it++){
        const uint4 v  = sp[it*64 + l];        // words i=it*256+4l+j ; jp=i>>4, b=i&15
        const int jp0  = it*16 + (l>>2);
        const int b0   = (l&3)*4;
        hw[((b0  )*128 + qq*32 + jp0) ^ (((b0  )&7)<<2)] = v.x;
        hw[((b0+1)*128 + qq*32 + jp0) ^ (((b0+1)&7)<<2)] = v.y;
        hw[((b0+2)*128 + qq*32 + jp0) ^ (((b0+2)&7)<<2)] = v.z;
        hw[((b0+3)*128 + qq*32 + jp0) ^ (((b0+3)&7)<<2)] = v.w;
      }
    }
    __syncthreads();   // h(s+1) complete in hw
  }

  // classifier: q==0 blocks hold full final h in hbuf[0] (SEQ even)
  if (q == 0 && tid < 160){
    const int b = tid/10, j = tid - b*10;
    const unsigned int* hf = hbuf[SEQ&1];
    float sum = bcls[j];
    for (int cp=0; cp<128; cp++){
      U32H2 v; v.u = hf[(b*128 + cp) ^ ((b&7)<<2)];
      sum += Wcls[j*NHID + cp*2]     * (float)v.h[0]
           + Wcls[j*NHID + cp*2 + 1] * (float)v.h[1];
    }
    out[(grp*16+b)*10 + j] = sum;
  }
}

extern "C" void kernel_launch(void* const* d_in, const int* in_sizes, int n_in,
                              void* d_out, int out_size, void* d_ws, size_t ws_size,
                              hipStream_t stream){
  const float* x    = (const float*)d_in[0];
  const float* h0   = (const float*)d_in[1];
  const float* c0   = (const float*)d_in[2];
  const float* Wi   = (const float*)d_in[3];
  const float* bi   = (const float*)d_in[4];
  const float* bh_  = (const float*)d_in[6];
  const float* Wh   = (const float*)d_in[5];
  const float* Wcls = (const float*)d_in[7];
  const float* bcls = (const float*)d_in[8];

  char* ws = (char*)d_ws;
  int*          flags  = (int*)ws;                     // 64 flags, 64B apart: 4096 B
  unsigned int* slices = (unsigned int*)(ws + 4096);   // 2 x 64 x 512 u32 = 262144 B

  hipMemsetAsync(flags, 0, 4096, stream);  // flags must start at 0 every call
  hipLaunchKernelGGL(lstm_seq, dim3(NBLK), dim3(NTHR), 0, stream,
                     x, h0, c0, Wi, bi, Wh, bh_, Wcls, bcls,
                     flags, slices, (float*)d_out);
}

// Round 4
// 2137.593 us; speedup vs baseline: 2.9528x; 1.6806x over previous
//
#include <hip/hip_runtime.h>

#define SEQ   1024
#define DIN   64
#define NHID  256
#define NBLK  64
#define NTHR  512

typedef _Float16 f16x8 __attribute__((ext_vector_type(8)));
typedef float    f32x4 __attribute__((ext_vector_type(4)));
typedef unsigned long long u64;

#define MFMA16(a,b,c) __builtin_amdgcn_mfma_f32_16x16x32_f16((a),(b),(c),0,0,0)

__device__ __forceinline__ float sigm(float v){
  return __builtin_amdgcn_rcpf(1.f + __expf(-v));
}
__device__ __forceinline__ float tanh_f(float v){
  return 1.f - 2.f*__builtin_amdgcn_rcpf(__expf(2.f*v)+1.f);
}

__device__ __forceinline__ f16x8 cvt8(f32x4 a, f32x4 b){
  f16x8 r;
  r[0]=(_Float16)a[0]; r[1]=(_Float16)a[1]; r[2]=(_Float16)a[2]; r[3]=(_Float16)a[3];
  r[4]=(_Float16)b[0]; r[5]=(_Float16)b[1]; r[6]=(_Float16)b[2]; r[7]=(_Float16)b[3];
  return r;
}

union U32H2 { unsigned int u; _Float16 h[2]; unsigned short us[2]; };

// 64 blocks = 16 groups (16 batch rows) x 4 members (64 hidden cols).
// Exchange protocol: tag-in-payload. Each lane publishes ONE u64
// {hi = s+1, lo = 2xf16 colpair} as a relaxed agent-scope atomic store.
// Readers poll the data words directly (relaxed u64 atomic loads, same-XCD L2).
// No flags, no acquire/release cache maintenance, no pre-publish barrier.
// Slices are zeroed by hipMemsetAsync each launch, so stale tags never match.
__global__ void __launch_bounds__(NTHR, 2)
lstm_seq(const float* __restrict__ x, const float* __restrict__ h0,
         const float* __restrict__ c0, const float* __restrict__ Wi,
         const float* __restrict__ bi, const float* __restrict__ Wh,
         const float* __restrict__ bh, const float* __restrict__ Wcls,
         const float* __restrict__ bcls,
         u64* __restrict__ slices, float* __restrict__ out)
{
  // h double-buffer: [parity][batch(16) x 128 u32 (256 f16 cols)], word ^= (b&7)<<2
  __shared__ __align__(16) unsigned int hbuf[2][16*128];

  const int bid = blockIdx.x;
  const int grp = bid & 15;          // batch group (16 rows)
  const int q   = bid >> 4;          // hidden quarter 0..3
  const int tid = threadIdx.x;
  const int w   = tid >> 6;          // wave 0..7
  const int l   = tid & 63;
  const int l15 = l & 15;
  const int lhi = l >> 4;

  // ---- A-frags: weights, register-resident f16, permuted rows ----
  // m-tile mt = w*2+t ; A-row mr=l15 ; jl = (mt>>1)*8 + ((mr>>2)<<1) + (mt&1)
  // original weight row = (mr&3)*256 + q*64 + jl  (gate = mr&3)
  f16x8 wa[2][8], xa[2][2];
#pragma unroll
  for (int t=0;t<2;t++){
    const int mt  = w*2 + t;
    const int mr  = l15;
    const int jl  = (mt>>1)*8 + ((mr>>2)<<1) + (mt&1);
    const int row = (mr&3)*NHID + q*64 + jl;
#pragma unroll
    for (int kt=0;kt<8;kt++){
      const float* p = Wh + row*NHID + kt*32 + lhi*8;
      wa[t][kt] = cvt8(*(const f32x4*)p, *(const f32x4*)(p+4));
    }
#pragma unroll
    for (int kt=0;kt<2;kt++){
      const float* p = Wi + row*DIN + kt*32 + lhi*8;
      xa[t][kt] = cvt8(*(const f32x4*)p, *(const f32x4*)(p+4));
    }
  }

  // per-lane bias (acc init) and cell state; lane owns jl = w*8 + lhi*2 + t
  f32x4 binit0, binit1; float c[2];
#pragma unroll
  for (int t=0;t<2;t++){
    const int jl = w*8 + lhi*2 + t;
    f32x4 bv;
#pragma unroll
    for (int g=0; g<4; g++)
      bv[g] = bi[g*NHID + q*64 + jl] + bh[g*NHID + q*64 + jl];
    if (t==0) binit0 = bv; else binit1 = bv;
    c[t] = c0[(size_t)(grp*16+l15)*NHID + q*64 + jl];
  }

  // h0 -> hbuf[0]
  for (int i=tid; i<16*128; i+=NTHR){
    const int b = i>>7, cp = i&127;
    U32H2 pk;
    pk.h[0] = (_Float16)h0[(size_t)(grp*16+b)*NHID + cp*2];
    pk.h[1] = (_Float16)h0[(size_t)(grp*16+b)*NHID + cp*2 + 1];
    hbuf[0][i ^ ((b&7)<<2)] = pk.u;
  }
  __syncthreads();

  // x(0) load, acc preinit (bias + x-proj), then prefetch x(1)
  const float* xrow = x + (size_t)(grp*16 + l15) * (SEQ*DIN);
  f32x4 xp0,xp1,xp2,xp3;
  {
    const float* p = xrow + lhi*8;
    xp0 = *(const f32x4*)p;      xp1 = *(const f32x4*)(p+4);
    xp2 = *(const f32x4*)(p+32); xp3 = *(const f32x4*)(p+36);
  }
  f32x4 acc0, acc1;
  {
    f16x8 xb0 = cvt8(xp0, xp1), xb1 = cvt8(xp2, xp3);
    acc0 = MFMA16(xa[0][0], xb0, binit0);
    acc0 = MFMA16(xa[0][1], xb1, acc0);
    acc1 = MFMA16(xa[1][0], xb0, binit1);
    acc1 = MFMA16(xa[1][1], xb1, acc1);
  }
  {
    const float* p = xrow + DIN + lhi*8;
    xp0 = *(const f32x4*)p;      xp1 = *(const f32x4*)(p+4);
    xp2 = *(const f32x4*)(p+32); xp3 = *(const f32x4*)(p+36);
  }

  for (int s=0; s<SEQ; s++){
    const unsigned int* hr = hbuf[s&1];
    unsigned int*       hw = hbuf[(s+1)&1];

    // B-frag reads (swizzled, balanced banks)
    f16x8 hb[8];
#pragma unroll
    for (int kt=0;kt<8;kt++){
      const int word = (l15*128 + kt*16 + lhi*4) ^ ((l15&7)<<2);
      hb[kt] = *(const f16x8*)(hr + word);
    }
    // recurrent MFMAs, k-split into two 4-deep chains per acc
    f32x4 a0 = acc0, a1 = acc1;
    f32x4 b0 = {0.f,0.f,0.f,0.f}, b1 = {0.f,0.f,0.f,0.f};
#pragma unroll
    for (int kt=0;kt<4;kt++){
      a0 = MFMA16(wa[0][kt],   hb[kt],   a0);
      a1 = MFMA16(wa[1][kt],   hb[kt],   a1);
      b0 = MFMA16(wa[0][kt+4], hb[kt+4], b0);
      b1 = MFMA16(wa[1][kt+4], hb[kt+4], b1);
    }
    acc0 = a0 + b0;
    acc1 = a1 + b1;

    // ---- pointwise in-register (r: 0=f,1=i,2=g,3=o) ----
    U32H2 pk;
    {
      const float f0 = sigm (acc0[0]);
      const float i0 = sigm (acc0[1]);
      const float g0 = tanh_f(acc0[2]);
      const float o0 = sigm (acc0[3]);
      c[0] = c[0]*f0 + i0*g0;
      pk.h[0] = (_Float16)(tanh_f(c[0])*o0);
      const float f1 = sigm (acc1[0]);
      const float i1 = sigm (acc1[1]);
      const float g1 = tanh_f(acc1[2]);
      const float o1 = sigm (acc1[3]);
      c[1] = c[1]*f1 + i1*g1;
      pk.h[1] = (_Float16)(tanh_f(c[1])*o1);
    }
    // publish immediately: one u64 {tag, payload} per lane, coalesced per wave
    {
      const u64 word = ((u64)(unsigned)(s+1) << 32) | (u64)pk.u;
      __hip_atomic_store(slices + ((size_t)(s&1)*NBLK + grp*4 + q)*512 + w*64 + l,
                         word, __ATOMIC_RELAXED, __HIP_MEMORY_SCOPE_AGENT);
    }
    // own colpair -> hw LDS
    {
      const int jp = w*4 + lhi;
      hw[(l15*128 + q*32 + jp) ^ ((l15&7)<<2)] = pk.u;
    }
    // next-step input projection (off the critical path: overlaps partner wait)
    {
      f16x8 xb0 = cvt8(xp0, xp1), xb1 = cvt8(xp2, xp3);
      acc0 = MFMA16(xa[0][0], xb0, binit0);
      acc0 = MFMA16(xa[0][1], xb1, acc0);
      acc1 = MFMA16(xa[1][0], xb0, binit1);
      acc1 = MFMA16(xa[1][1], xb1, acc1);
    }
    {
      const int sn = (s < SEQ-2) ? s+2 : SEQ-1;
      const float* p = xrow + sn*DIN + lhi*8;
      xp0 = *(const f32x4*)p;      xp1 = *(const f32x4*)(p+4);
      xp2 = *(const f32x4*)(p+32); xp3 = *(const f32x4*)(p+36);
    }
    // exchange: every wave polls word w*64+l of each partner slice
    const unsigned tag = (unsigned)(s+1);
#pragma unroll
    for (int dq=1; dq<4; dq++){
      const int qq = (q + dq) & 3;
      const u64* sp = slices + ((size_t)(s&1)*NBLK + grp*4 + qq)*512 + w*64 + l;
      u64 v = __hip_atomic_load(sp, __ATOMIC_RELAXED, __HIP_MEMORY_SCOPE_AGENT);
      while ((unsigned)(v >> 32) != tag)
        v = __hip_atomic_load(sp, __ATOMIC_RELAXED, __HIP_MEMORY_SCOPE_AGENT);
      hw[(l15*128 + qq*32 + w*4 + lhi) ^ ((l15&7)<<2)] = (unsigned)v;
    }
    __syncthreads();   // h(s+1) complete in hw; also orders hw WAR across steps
  }

  // classifier: q==0 blocks hold full final h in hbuf[SEQ&1] = hbuf[0]
  if (q == 0 && tid < 160){
    const int b = tid/10, j = tid - b*10;
    const unsigned int* hf = hbuf[SEQ&1];
    float sum = bcls[j];
    for (int cp=0; cp<128; cp++){
      U32H2 v; v.u = hf[(b*128 + cp) ^ ((b&7)<<2)];
      sum += Wcls[j*NHID + cp*2]     * (float)v.h[0]
           + Wcls[j*NHID + cp*2 + 1] * (float)v.h[1];
    }
    out[(grp*16+b)*10 + j] = sum;
  }
}

extern "C" void kernel_launch(void* const* d_in, const int* in_sizes, int n_in,
                              void* d_out, int out_size, void* d_ws, size_t ws_size,
                              hipStream_t stream){
  const float* x    = (const float*)d_in[0];
  const float* h0   = (const float*)d_in[1];
  const float* c0   = (const float*)d_in[2];
  const float* Wi   = (const float*)d_in[3];
  const float* bi   = (const float*)d_in[4];
  const float* Wh   = (const float*)d_in[5];
  const float* bh   = (const float*)d_in[6];
  const float* Wcls = (const float*)d_in[7];
  const float* bcls = (const float*)d_in[8];

  u64* slices = (u64*)d_ws;   // 2 parities x 64 blocks x 512 u64 = 524288 B

  // zero tags every launch so stale values from prior replays never match
  hipMemsetAsync(slices, 0, 2*NBLK*512*sizeof(u64), stream);
  hipLaunchKernelGGL(lstm_seq, dim3(NBLK), dim3(NTHR), 0, stream,
                     x, h0, c0, Wi, bi, Wh, bh, Wcls, bcls,
                     slices, (float*)d_out);
}